// Round 1
// baseline (1057.787 us; speedup 1.0000x reference)
//
#include <hip/hip_runtime.h>

// Problem constants (from reference setup_inputs)
constexpr int kB = 256;
constexpr int kT = 2048;
constexpr int kI = 32;
constexpr int kH = 64;
constexpr int kO = 16;
constexpr int kPadL = 2;
constexpr int kPadR = 3;
constexpr int kTp = kT + kPadL + kPadR;  // 2053
constexpr int kCT = 64;                  // time-chunk staged in LDS (8 KB)

// One workgroup (single wave of 64) per batch element; lane = hidden unit h.
// W_ih row (32 f32) and W_hh row (64 f32) live in VGPRs for the whole kernel.
// Per step: h broadcast via LDS (write 1, read 16x b128 broadcast), x row via
// LDS broadcast (8x b128), 96 FMAs, overflow-safe tanh, accumulate h_sum.
__global__ __launch_bounds__(64) void rnn_fused(
    const float* __restrict__ x,
    const float* __restrict__ W_ih,
    const float* __restrict__ W_hh,
    const float* __restrict__ b_ih,
    const float* __restrict__ b_hh,
    const float* __restrict__ W_fc,
    const float* __restrict__ b_fc,
    float* __restrict__ out)
{
  const int b = blockIdx.x;
  const int lane = threadIdx.x;  // h index

  __shared__ __align__(16) float xbuf[kCT * kI];  // 8 KB staged x chunk
  __shared__ __align__(16) float hbuf[kH];        // h broadcast buffer
  __shared__ __align__(16) float aggbuf[kH];      // epilogue

  // ---- load per-lane weight rows into registers ----
  float wih[kI];
#pragma unroll
  for (int i = 0; i < kI; i += 4) {
    float4 v = *(const float4*)(W_ih + lane * kI + i);
    wih[i + 0] = v.x; wih[i + 1] = v.y; wih[i + 2] = v.z; wih[i + 3] = v.w;
  }
  float whh[kH];
#pragma unroll
  for (int j = 0; j < kH; j += 4) {
    float4 v = *(const float4*)(W_hh + lane * kH + j);
    whh[j + 0] = v.x; whh[j + 1] = v.y; whh[j + 2] = v.z; whh[j + 3] = v.w;
  }
  const float bias = b_ih[lane] + b_hh[lane];

  float h = 0.0f;
  float hsum = 0.0f;

  // Overflow-safe fast tanh: t = exp(-2|z|); r = (1-t)/(1+t); restore sign.
  auto fast_tanh = [](float z) {
    float t = __expf(-2.0f * fabsf(z));
    float r = (1.0f - t) * __builtin_amdgcn_rcpf(1.0f + t);
    return z < 0.0f ? -r : r;
  };

  // One recurrence step. xrow == nullptr (compile-time folded) for pad steps.
  auto step = [&](const float* xrow) {
    hbuf[lane] = h;
    float acc = bias;
    __syncthreads();  // make all lanes' h visible (single wave: cheap)
    if (xrow) {
#pragma unroll
      for (int i = 0; i < kI; i += 4) {
        float4 xv = *(const float4*)(xrow + i);  // broadcast LDS read
        acc = fmaf(wih[i + 0], xv.x, acc);
        acc = fmaf(wih[i + 1], xv.y, acc);
        acc = fmaf(wih[i + 2], xv.z, acc);
        acc = fmaf(wih[i + 3], xv.w, acc);
      }
    }
    float a0 = 0.f, a1 = 0.f, a2 = 0.f, a3 = 0.f;
#pragma unroll
    for (int j = 0; j < kH; j += 16) {
      float4 va = *(const float4*)(hbuf + j + 0);
      float4 vb = *(const float4*)(hbuf + j + 4);
      float4 vc = *(const float4*)(hbuf + j + 8);
      float4 vd = *(const float4*)(hbuf + j + 12);
      a0 = fmaf(whh[j + 0], va.x, a0);
      a1 = fmaf(whh[j + 1], va.y, a1);
      a2 = fmaf(whh[j + 2], va.z, a2);
      a3 = fmaf(whh[j + 3], va.w, a3);
      a0 = fmaf(whh[j + 4], vb.x, a0);
      a1 = fmaf(whh[j + 5], vb.y, a1);
      a2 = fmaf(whh[j + 6], vb.z, a2);
      a3 = fmaf(whh[j + 7], vb.w, a3);
      a0 = fmaf(whh[j + 8], vc.x, a0);
      a1 = fmaf(whh[j + 9], vc.y, a1);
      a2 = fmaf(whh[j + 10], vc.z, a2);
      a3 = fmaf(whh[j + 11], vc.w, a3);
      a0 = fmaf(whh[j + 12], vd.x, a0);
      a1 = fmaf(whh[j + 13], vd.y, a1);
      a2 = fmaf(whh[j + 14], vd.z, a2);
      a3 = fmaf(whh[j + 15], vd.w, a3);
    }
    float z = acc + ((a0 + a1) + (a2 + a3));
    h = fast_tanh(z);
    hsum += h;
    // No trailing barrier needed: the next step's hbuf write data-depends on
    // this step's LDS reads (lockstep single wave), so WAR is ordered.
  };

  // ---- software-pipelined x staging: preload chunk 0 into registers ----
  const float* xb = x + (size_t)b * kT * kI;
  float4 xr[8];
#pragma unroll
  for (int k = 0; k < 8; ++k)
    xr[k] = *(const float4*)(xb + (k * 64 + lane) * 4);

  // left padding: 2 steps with x = 0
  step(nullptr);
  step(nullptr);

  constexpr int kNC = kT / kCT;  // 32 chunks
  for (int c = 0; c < kNC; ++c) {
    __syncthreads();  // prior chunk's xbuf reads done before overwrite
#pragma unroll
    for (int k = 0; k < 8; ++k)
      *(float4*)(&xbuf[(k * 64 + lane) * 4]) = xr[k];
    __syncthreads();  // xbuf visible to all lanes
    if (c + 1 < kNC) {
      const float* src = xb + (size_t)(c + 1) * kCT * kI;
#pragma unroll
      for (int k = 0; k < 8; ++k)
        xr[k] = *(const float4*)(src + (k * 64 + lane) * 4);  // in flight during steps
    }
#pragma unroll 2
    for (int ct = 0; ct < kCT; ++ct) {
      step(&xbuf[ct * kI]);
    }
  }

  // right padding: 3 steps with x = 0
  step(nullptr);
  step(nullptr);
  step(nullptr);

  // ---- epilogue: mean over Tp, FC (16x64) + ReLU ----
  aggbuf[lane] = hsum * (1.0f / (float)kTp);
  __syncthreads();
  if (lane < kO) {
    float acc = b_fc[lane];
    const float* wf = W_fc + lane * kH;
#pragma unroll
    for (int j = 0; j < kH; ++j)
      acc = fmaf(wf[j], aggbuf[j], acc);
    out[b * kO + lane] = fmaxf(acc, 0.0f);
  }
}

extern "C" void kernel_launch(void* const* d_in, const int* in_sizes, int n_in,
                              void* d_out, int out_size, void* d_ws, size_t ws_size,
                              hipStream_t stream) {
  const float* x    = (const float*)d_in[0];
  const float* W_ih = (const float*)d_in[1];
  const float* W_hh = (const float*)d_in[2];
  const float* b_ih = (const float*)d_in[3];
  const float* b_hh = (const float*)d_in[4];
  const float* W_fc = (const float*)d_in[5];
  const float* b_fc = (const float*)d_in[6];
  float* out = (float*)d_out;

  rnn_fused<<<dim3(kB), dim3(64), 0, stream>>>(x, W_ih, W_hh, b_ih, b_hh,
                                               W_fc, b_fc, out);
}

// Round 2
// 850.573 us; speedup vs baseline: 1.2436x; 1.2436x over previous
//
#include <hip/hip_runtime.h>

// Problem constants (from reference setup_inputs)
constexpr int kB = 256;
constexpr int kT = 2048;
constexpr int kI = 32;
constexpr int kH = 64;
constexpr int kO = 16;
constexpr int kPadL = 2;
constexpr int kPadR = 3;
constexpr int kTp = kT + kPadL + kPadR;  // 2053
constexpr int kCT = 64;                  // time-chunk staged in LDS (8 KB)
constexpr int kNC = kT / kCT;            // 32 chunks

typedef float v2f __attribute__((ext_vector_type(2)));

// Full-rate packed fp32 FMA (CDNA3/4): d = a*b + d, two lanes per instr.
__device__ __forceinline__ void pk_fma(v2f& d, v2f a, v2f b) {
  asm("v_pk_fma_f32 %0, %1, %2, %0" : "+v"(d) : "v"(a), "v"(b));
}

// Single-wave workgroup: LDS ordering needs only lgkmcnt, never s_barrier
// (which would also drain vmcnt(0), stalling on the global prefetch queue).
__device__ __forceinline__ void lds_fence() {
  asm volatile("s_waitcnt lgkmcnt(0)" ::: "memory");
}

// One workgroup (1 wave) per batch element; lane = hidden unit.
// Representation trick: communicate r_t = 1/(1+e^{2 z_t}) via LDS instead of
// h_t = tanh(z_t) = 1 - 2 r_t.  Fold the affine part into the weights:
//   2*z_i = [2(b_ih+b_hh) + 2*rowsum_i] + sum_j (2*W_ih[i][j]) x_j
//                                       + sum_j (-4*W_hh[i][j]) r_j
// so the step tail is just  t = __expf(2z);  r = rcp(1+t).
// h_sum = Tp - 2*sum(r).
__global__ __launch_bounds__(64) void rnn_fused(
    const float* __restrict__ x,
    const float* __restrict__ W_ih,
    const float* __restrict__ W_hh,
    const float* __restrict__ b_ih,
    const float* __restrict__ b_hh,
    const float* __restrict__ W_fc,
    const float* __restrict__ b_fc,
    float* __restrict__ out)
{
  const int b = blockIdx.x;
  const int lane = threadIdx.x;  // hidden unit index

  __shared__ __align__(16) float xbuf[kCT * kI];  // 8 KB staged x chunk
  __shared__ __align__(16) float rbuf[kH];        // r broadcast buffer
  __shared__ __align__(16) float aggbuf[kH];      // epilogue

  // ---- per-lane weight rows, pre-scaled ----
  v2f wh2[kH / 2];
  float rowsum = 0.0f;
#pragma unroll
  for (int j = 0; j < kH; j += 4) {
    float4 v = *(const float4*)(W_hh + lane * kH + j);
    rowsum += (v.x + v.y) + (v.z + v.w);
    wh2[j / 2 + 0] = v2f{-4.0f * v.x, -4.0f * v.y};
    wh2[j / 2 + 1] = v2f{-4.0f * v.z, -4.0f * v.w};
  }
  v2f wi2[kI / 2];
#pragma unroll
  for (int i = 0; i < kI; i += 4) {
    float4 v = *(const float4*)(W_ih + lane * kI + i);
    wi2[i / 2 + 0] = v2f{2.0f * v.x, 2.0f * v.y};
    wi2[i / 2 + 1] = v2f{2.0f * v.z, 2.0f * v.w};
  }
  const float bias2 = 2.0f * (b_ih[lane] + b_hh[lane] + rowsum);

  float r = 0.5f;     // represents h0 = 0
  float rsum = 0.0f;  // sum of produced r's
  v2f xc0 = v2f{0.0f, 0.0f}, xc1 = v2f{0.0f, 0.0f};  // x-dot for CURRENT step

  // One recurrence step. Uses xc (x contribution of this step); computes the
  // NEXT step's x contribution from xnrow (or zero) AFTER the critical
  // ds_write + rbuf-read issue, so it fills LDS-return latency.
  auto step = [&](const float4* xnrow) {
    rbuf[lane] = r;   // ds_write_b32 — the head of the serial chain
    lds_fence();      // write visible (single wave, in-order DS pipe)
    const float4* rb4 = (const float4*)rbuf;
    v2f h0 = {0, 0}, h1 = {0, 0}, h2 = {0, 0}, h3 = {0, 0};
    v2f h4 = {0, 0}, h5 = {0, 0}, h6 = {0, 0}, h7 = {0, 0};
#pragma unroll
    for (int q = 0; q < 4; ++q) {
      float4 A = rb4[4 * q + 0];
      float4 B = rb4[4 * q + 1];
      float4 C = rb4[4 * q + 2];
      float4 D = rb4[4 * q + 3];
      pk_fma(h0, wh2[8 * q + 0], v2f{A.x, A.y});
      pk_fma(h1, wh2[8 * q + 1], v2f{A.z, A.w});
      pk_fma(h2, wh2[8 * q + 2], v2f{B.x, B.y});
      pk_fma(h3, wh2[8 * q + 3], v2f{B.z, B.w});
      pk_fma(h4, wh2[8 * q + 4], v2f{C.x, C.y});
      pk_fma(h5, wh2[8 * q + 5], v2f{C.z, C.w});
      pk_fma(h6, wh2[8 * q + 6], v2f{D.x, D.y});
      pk_fma(h7, wh2[8 * q + 7], v2f{D.z, D.w});
    }
    // next step's x projection — off the critical path
    v2f xn0 = v2f{0.0f, 0.0f}, xn1 = v2f{0.0f, 0.0f};
    if (xnrow) {
#pragma unroll
      for (int i2 = 0; i2 < 8; ++i2) {
        float4 v = xnrow[i2];
        pk_fma(xn0, wi2[2 * i2 + 0], v2f{v.x, v.y});
        pk_fma(xn1, wi2[2 * i2 + 1], v2f{v.z, v.w});
      }
    }
    v2f s = (((h0 + h1) + (h2 + h3)) + ((h4 + h5) + (h6 + h7))) + (xc0 + xc1);
    float z2 = bias2 + s.x + s.y;       // = 2*z
    float t = __expf(z2);               // e^{2z}; inf is graceful (r -> 0)
    r = __builtin_amdgcn_rcpf(1.0f + t);
    rsum += r;
    xc0 = xn0;
    xc1 = xn1;
  };

  // ---- prefetch chunk 0 into registers ----
  const float* xb = x + (size_t)b * kT * kI;
  float4 xr[8];
#pragma unroll
  for (int k = 0; k < 8; ++k)
    xr[k] = *(const float4*)(xb + (k * 64 + lane) * 4);

  // left padding: 2 steps with x = 0 (xc starts at 0)
  step(nullptr);
  step(nullptr);

  for (int c = 0; c < kNC; ++c) {
    lds_fence();  // WAR: prior chunk's xbuf reads are complete
#pragma unroll
    for (int k = 0; k < 8; ++k)
      ((float4*)xbuf)[k * 64 + lane] = xr[k];  // compiler waits vmcnt here
    lds_fence();  // staging visible before reads
    if (c + 1 < kNC) {
      const float* src = xb + (size_t)(c + 1) * kCT * kI;
#pragma unroll
      for (int k = 0; k < 8; ++k)
        xr[k] = *(const float4*)(src + (k * 64 + lane) * 4);  // in flight
    }
    // prologue: x contribution of this chunk's step 0
    {
      const float4* row0 = (const float4*)xbuf;
      v2f a0 = v2f{0.0f, 0.0f}, a1 = v2f{0.0f, 0.0f};
#pragma unroll
      for (int i2 = 0; i2 < 8; ++i2) {
        float4 v = row0[i2];
        pk_fma(a0, wi2[2 * i2 + 0], v2f{v.x, v.y});
        pk_fma(a1, wi2[2 * i2 + 1], v2f{v.z, v.w});
      }
      xc0 = a0;
      xc1 = a1;
    }
#pragma unroll 3
    for (int ct = 0; ct < kCT - 1; ++ct)
      step(((const float4*)xbuf) + (ct + 1) * 8);
    step(nullptr);  // ct = 63: next x comes from the next chunk's prologue
  }

  // right padding: 3 steps with x = 0
  step(nullptr);
  step(nullptr);
  step(nullptr);

  // ---- epilogue: mean over Tp, FC (16x64) + ReLU ----
  // hsum = Tp - 2*rsum  ->  aggregated = 1 - 2*rsum/Tp
  aggbuf[lane] = 1.0f - 2.0f * rsum * (1.0f / (float)kTp);
  lds_fence();
  if (lane < kO) {
    float acc = b_fc[lane];
    const float* wf = W_fc + lane * kH;
#pragma unroll
    for (int j = 0; j < kH; ++j)
      acc = fmaf(wf[j], aggbuf[j], acc);
    out[b * kO + lane] = fmaxf(acc, 0.0f);
  }
}

extern "C" void kernel_launch(void* const* d_in, const int* in_sizes, int n_in,
                              void* d_out, int out_size, void* d_ws, size_t ws_size,
                              hipStream_t stream) {
  const float* x    = (const float*)d_in[0];
  const float* W_ih = (const float*)d_in[1];
  const float* W_hh = (const float*)d_in[2];
  const float* b_ih = (const float*)d_in[3];
  const float* b_hh = (const float*)d_in[4];
  const float* W_fc = (const float*)d_in[5];
  const float* b_fc = (const float*)d_in[6];
  float* out = (float*)d_out;

  rnn_fused<<<dim3(kB), dim3(64), 0, stream>>>(x, W_ih, W_hh, b_ih, b_hh,
                                               W_fc, b_fc, out);
}